// Round 6
// baseline (136.686 us; speedup 1.0000x reference)
//
#include <hip/hip_runtime.h>
#include <hip/hip_bf16.h>
#include <math.h>

#define CHN 192
#define BATCHN 65536
#define NBLOCKS 4096
#define ROWS_PER_BLOCK (BATCHN / NBLOCKS)   // 16
#define NW 43                                // transformed-weight slots per channel

// ---- fast device math -------------------------------------------------------
__device__ __forceinline__ float fast_rcp(float x)  { return __builtin_amdgcn_rcpf(x); }
__device__ __forceinline__ void pin(float& v) { asm volatile("" : "+v"(v)); }

__device__ __forceinline__ float softplus_acc(float h) {
    if (h > 20.0f) return h;
    return log1pf(expf(h));
}

// ---- rational tanh (Eigen coefficients), PAIRED: 2 tanhs share ONE v_rcp ----
// All coefficients live in PINNED VGPRs: VOP3 fma cannot encode literals, and
// without pinning the compiler re-materializes v_mov constants per use inside
// the row loop (round-5 post-mortem: ~550 unexplained cyc/elem = those movs).
#define TCLAMP 7.90531110763549805f
#define A1  4.89352455891786e-03f
#define A3  6.37261928875436e-04f
#define A5  1.48572235717979e-05f
#define A7  5.12229709037114e-08f
#define A9  -8.60467152213735e-11f
#define A11 2.00018790482477e-13f
#define A13 -2.76076847742355e-16f
#define B0  4.89352518554385e-03f
#define B2  2.26843463243900e-03f
#define B4  1.18534705686654e-04f
#define B6  1.19825839466702e-06f

struct Coef {
    float a1, a3, a5, a7, a9, a11, a13;
    float b0, b2, b4, b6;
    float lo, hi;        // clamp bounds for v_med3
};

__device__ __forceinline__ void tanh2(const Coef& K,
                                      float tp_in, float tm_in,
                                      float& yp, float& ym) {
    float tp = __builtin_amdgcn_fmed3f(tp_in, K.lo, K.hi);   // 1 inst clamp
    float tm = __builtin_amdgcn_fmed3f(tm_in, K.lo, K.hi);
    float up = tp * tp, um = tm * tm;
    float Pp = fmaf(up, K.a13, K.a11);
    float Pm = fmaf(um, K.a13, K.a11);
    Pp = fmaf(up, Pp, K.a9);  Pm = fmaf(um, Pm, K.a9);
    Pp = fmaf(up, Pp, K.a7);  Pm = fmaf(um, Pm, K.a7);
    Pp = fmaf(up, Pp, K.a5);  Pm = fmaf(um, Pm, K.a5);
    Pp = fmaf(up, Pp, K.a3);  Pm = fmaf(um, Pm, K.a3);
    Pp = fmaf(up, Pp, K.a1);  Pm = fmaf(um, Pm, K.a1);
    float Qp = fmaf(up, K.b6, K.b4);
    float Qm = fmaf(um, K.b6, K.b4);
    Qp = fmaf(up, Qp, K.b2);  Qm = fmaf(um, Qm, K.b2);
    Qp = fmaf(up, Qp, K.b0);  Qm = fmaf(um, Qm, K.b0);
    float np = tp * Pp, nm = tm * Pm;
    float r  = fast_rcp(Qp * Qm);           // ONE trans op for both tanhs
    yp = np * Qm * r;
    ym = nm * Qp * r;
}

// ============================================================================
// Kernel A: apply softplus/tanh to weights ONCE, write slot-major to ws.
// ws layout: ws[s*CHN + c], s in [0,43):
//   0-2 W0 | 3-5 B0 | 6-8 T0 | 9-17 W1 | 18-20 B1 | 21-23 T1
//   24-32 W2 | 33-35 B2 | 36-38 T2 | 39-41 W3 | 42 b3
// ============================================================================
__global__ __launch_bounds__(CHN) void weights_kernel(
    const float* __restrict__ a0, const float* __restrict__ a1, const float* __restrict__ a2,
    const float* __restrict__ b0, const float* __restrict__ b1, const float* __restrict__ b2,
    const float* __restrict__ b3,
    const float* __restrict__ H0, const float* __restrict__ H1, const float* __restrict__ H2,
    const float* __restrict__ H3,
    float* __restrict__ ws)
{
    const int c = threadIdx.x;
#pragma unroll
    for (int i = 0; i < 3; ++i) {
        ws[(0  + i) * CHN + c] = softplus_acc(H0[c * 3 + i]);
        ws[(3  + i) * CHN + c] = b0[c * 3 + i];
        ws[(6  + i) * CHN + c] = tanhf(a0[c * 3 + i]);
        ws[(18 + i) * CHN + c] = b1[c * 3 + i];
        ws[(21 + i) * CHN + c] = tanhf(a1[c * 3 + i]);
        ws[(33 + i) * CHN + c] = b2[c * 3 + i];
        ws[(36 + i) * CHN + c] = tanhf(a2[c * 3 + i]);
        ws[(39 + i) * CHN + c] = softplus_acc(H3[c * 3 + i]);
    }
#pragma unroll
    for (int i = 0; i < 9; ++i) {
        ws[(9  + i) * CHN + c] = softplus_acc(H1[c * 9 + i]);
        ws[(24 + i) * CHN + c] = softplus_acc(H2[c * 9 + i]);
    }
    ws[42 * CHN + c] = b3[c];
}

// ============================================================================
// Kernel B: zero libm, zero literals in the hot loop.
// ============================================================================
__device__ __forceinline__ float density_pair(const float* __restrict__ W,
                                              const Coef& K, float xv) {
    float xp = xv + 0.5f, xm = xv - 0.5f;
    float vp[3], vm[3];
#pragma unroll
    for (int i = 0; i < 3; ++i) {
        float tp = fmaf(W[0 + i], xp, W[3 + i]);
        float tm = fmaf(W[0 + i], xm, W[3 + i]);
        float yp, ym; tanh2(K, tp, tm, yp, ym);
        vp[i] = fmaf(W[6 + i], yp, tp);
        vm[i] = fmaf(W[6 + i], ym, tm);
    }
    float zp[3], zm[3];
#pragma unroll
    for (int p = 0; p < 3; ++p) {
        float tp = W[18 + p], tm = W[18 + p];
#pragma unroll
        for (int i = 0; i < 3; ++i) {
            tp = fmaf(vp[i], W[9 + i * 3 + p], tp);
            tm = fmaf(vm[i], W[9 + i * 3 + p], tm);
        }
        float yp, ym; tanh2(K, tp, tm, yp, ym);
        zp[p] = fmaf(W[21 + p], yp, tp);
        zm[p] = fmaf(W[21 + p], ym, tm);
    }
    float up3[3], um3[3];
#pragma unroll
    for (int p = 0; p < 3; ++p) {
        float tp = W[33 + p], tm = W[33 + p];
#pragma unroll
        for (int i = 0; i < 3; ++i) {
            tp = fmaf(zp[i], W[24 + i * 3 + p], tp);
            tm = fmaf(zm[i], W[24 + i * 3 + p], tm);
        }
        float yp, ym; tanh2(K, tp, tm, yp, ym);
        up3[p] = fmaf(W[36 + p], yp, tp);
        um3[p] = fmaf(W[36 + p], ym, tm);
    }
    float sp = W[42], sm = W[42];
#pragma unroll
    for (int i = 0; i < 3; ++i) {
        sp = fmaf(up3[i], W[39 + i], sp);
        sm = fmaf(um3[i], W[39 + i], sm);
    }
    // sigmoid(sp) - sigmoid(sm) = 0.5*(tanh(sp/2) - tanh(sm/2))
    float hp, hm; tanh2(K, 0.5f * sp, 0.5f * sm, hp, hm);
    return 0.5f * (hp - hm);
}

__global__ __launch_bounds__(CHN) void density_kernel(
    const float* __restrict__ x,
    const float* __restrict__ wt,
    float* __restrict__ out)
{
    const int c = threadIdx.x;          // thread <-> channel

    float W[NW];
#pragma unroll
    for (int s = 0; s < NW; ++s) W[s] = wt[s * CHN + c];   // 43 coalesced dwords
#pragma unroll
    for (int s = 0; s < NW; ++s) pin(W[s]);                // keep register-resident

    // ---- polynomial coefficients in pinned VGPRs (once per thread) ----
    Coef K;
    K.a1 = A1; K.a3 = A3; K.a5 = A5; K.a7 = A7; K.a9 = A9; K.a11 = A11; K.a13 = A13;
    K.b0 = B0; K.b2 = B2; K.b4 = B4; K.b6 = B6;
    K.lo = -TCLAMP; K.hi = TCLAMP;
    pin(K.a1); pin(K.a3); pin(K.a5); pin(K.a7); pin(K.a9); pin(K.a11); pin(K.a13);
    pin(K.b0); pin(K.b2); pin(K.b4); pin(K.b6);
    pin(K.lo); pin(K.hi);

    const int b_start = blockIdx.x * ROWS_PER_BLOCK;
#pragma unroll 2
    for (int r = 0; r < ROWS_PER_BLOCK; ++r) {
        const int idx = (b_start + r) * CHN + c;
        out[idx] = density_pair(W, K, x[idx]);
    }
}

extern "C" void kernel_launch(void* const* d_in, const int* in_sizes, int n_in,
                              void* d_out, int out_size, void* d_ws, size_t ws_size,
                              hipStream_t stream) {
    const float* x  = (const float*)d_in[0];
    const float* a0 = (const float*)d_in[1];
    const float* a1 = (const float*)d_in[2];
    const float* a2 = (const float*)d_in[3];
    const float* b0 = (const float*)d_in[4];
    const float* b1 = (const float*)d_in[5];
    const float* b2 = (const float*)d_in[6];
    const float* b3 = (const float*)d_in[7];
    const float* H0 = (const float*)d_in[8];
    const float* H1 = (const float*)d_in[9];
    const float* H2 = (const float*)d_in[10];
    const float* H3 = (const float*)d_in[11];
    float* out = (float*)d_out;
    float* ws  = (float*)d_ws;   // needs NW*CHN*4 = 33 KB

    weights_kernel<<<1, CHN, 0, stream>>>(a0, a1, a2, b0, b1, b2, b3,
                                          H0, H1, H2, H3, ws);
    density_kernel<<<NBLOCKS, CHN, 0, stream>>>(x, ws, out);
}

// Round 8
// 112.368 us; speedup vs baseline: 1.2164x; 1.2164x over previous
//
#include <hip/hip_runtime.h>
#include <hip/hip_bf16.h>
#include <math.h>

#define CHN 192
#define BATCHN 65536
#define NBLOCKS 4096
#define ROWS_PER_BLOCK (BATCHN / NBLOCKS)   // 16
#define NW 43                                // transformed-weight slots per channel

typedef float v2f __attribute__((ext_vector_type(2)));

// ---- packed-FP32 primitives (VOP3P): the 2x-issue path hipcc won't emit ----
__device__ __forceinline__ v2f pk_fma(v2f a, v2f b, v2f c) {
    v2f d;
    asm("v_pk_fma_f32 %0, %1, %2, %3" : "=v"(d) : "v"(a), "v"(b), "v"(c));
    return d;
}
__device__ __forceinline__ v2f pk_mul(v2f a, v2f b) {
    v2f d;
    asm("v_pk_mul_f32 %0, %1, %2" : "=v"(d) : "v"(a), "v"(b));
    return d;
}

__device__ __forceinline__ float fast_rcp(float x)  { return __builtin_amdgcn_rcpf(x); }
__device__ __forceinline__ void pin2(v2f& v) { asm volatile("" : "+v"(v)); }
__device__ __forceinline__ void pinf(float& v) { asm volatile("" : "+v"(v)); }

__device__ __forceinline__ float softplus_acc(float h) {
    if (h > 20.0f) return h;
    return log1pf(expf(h));
}

// ---- rational tanh (Eigen coefficients), packed over the (+,-) branches ----
// CF_ prefix: round-7 compile failure was macro B2 colliding with WP::B2.
#define CF_TCLAMP 7.90531110763549805f
#define CF_A1  4.89352455891786e-03f
#define CF_A3  6.37261928875436e-04f
#define CF_A5  1.48572235717979e-05f
#define CF_A7  5.12229709037114e-08f
#define CF_A9  -8.60467152213735e-11f
#define CF_A11 2.00018790482477e-13f
#define CF_A13 -2.76076847742355e-16f
#define CF_B0  4.89352518554385e-03f
#define CF_B2  2.26843463243900e-03f
#define CF_B4  1.18534705686654e-04f
#define CF_B6  1.19825839466702e-06f

struct Coef {
    v2f a1, a3, a5, a7, a9, a11, a13;   // dup'd packed constants
    v2f b0, b2, b4, b6;
    float lo, hi;                        // med3 clamp bounds (scalar)
};

// t = (t_plus, t_minus)  ->  (tanh(t_plus), tanh(t_minus)); ~16 issue slots.
__device__ __forceinline__ v2f tanh2p(const Coef& K, v2f t) {
    v2f tc;
    tc.x = __builtin_amdgcn_fmed3f(t.x, K.lo, K.hi);
    tc.y = __builtin_amdgcn_fmed3f(t.y, K.lo, K.hi);
    v2f u = pk_mul(tc, tc);
    v2f P = pk_fma(u, K.a13, K.a11);
    P = pk_fma(u, P, K.a9);
    P = pk_fma(u, P, K.a7);
    P = pk_fma(u, P, K.a5);
    P = pk_fma(u, P, K.a3);
    P = pk_fma(u, P, K.a1);
    v2f Q = pk_fma(u, K.b6, K.b4);
    Q = pk_fma(u, Q, K.b2);
    Q = pk_fma(u, Q, K.b0);
    v2f n = pk_mul(tc, P);
    v2f Qi;
    Qi.x = fast_rcp(Q.x);
    Qi.y = fast_rcp(Q.y);
    return pk_mul(n, Qi);
}

// ============================================================================
// Kernel A: apply softplus/tanh to weights ONCE, write slot-major to ws.
// ws layout: ws[s*CHN + c], s in [0,43):
//   0-2 W0 | 3-5 B0 | 6-8 T0 | 9-17 W1 | 18-20 B1 | 21-23 T1
//   24-32 W2 | 33-35 B2 | 36-38 T2 | 39-41 W3 | 42 b3
// ============================================================================
__global__ __launch_bounds__(CHN) void weights_kernel(
    const float* __restrict__ a0, const float* __restrict__ a1, const float* __restrict__ a2,
    const float* __restrict__ b0, const float* __restrict__ b1, const float* __restrict__ b2,
    const float* __restrict__ b3,
    const float* __restrict__ H0, const float* __restrict__ H1, const float* __restrict__ H2,
    const float* __restrict__ H3,
    float* __restrict__ ws)
{
    const int c = threadIdx.x;
#pragma unroll
    for (int i = 0; i < 3; ++i) {
        ws[(0  + i) * CHN + c] = softplus_acc(H0[c * 3 + i]);
        ws[(3  + i) * CHN + c] = b0[c * 3 + i];
        ws[(6  + i) * CHN + c] = tanhf(a0[c * 3 + i]);
        ws[(18 + i) * CHN + c] = b1[c * 3 + i];
        ws[(21 + i) * CHN + c] = tanhf(a1[c * 3 + i]);
        ws[(33 + i) * CHN + c] = b2[c * 3 + i];
        ws[(36 + i) * CHN + c] = tanhf(a2[c * 3 + i]);
        ws[(39 + i) * CHN + c] = softplus_acc(H3[c * 3 + i]);
    }
#pragma unroll
    for (int i = 0; i < 9; ++i) {
        ws[(9  + i) * CHN + c] = softplus_acc(H1[c * 9 + i]);
        ws[(24 + i) * CHN + c] = softplus_acc(H2[c * 9 + i]);
    }
    ws[42 * CHN + c] = b3[c];
}

// ============================================================================
// Kernel B: packed (+,-) evaluation; zero libm; ~200 issue slots per element.
// ============================================================================
struct WP {
    v2f pW0[3], pC0[3], pT0[3];   // pC0 = (B0 + .5*W0, B0 - .5*W0)  (asymmetric!)
    v2f pW1[9], pB1[3], pT1[3];
    v2f pW2[9], pB2[3], pT2[3];
    v2f pW3h[3], pb3h;            // x0.5 folded (sigmoid-diff = tanh(s/2) trick)
};

__device__ __forceinline__ float density_pair(const WP& w, const Coef& K, float xv) {
    v2f xd; xd.x = xv; xd.y = xv;

    v2f v[3];
#pragma unroll
    for (int i = 0; i < 3; ++i) {
        v2f t = pk_fma(w.pW0[i], xd, w.pC0[i]);
        v2f y = tanh2p(K, t);
        v[i] = pk_fma(w.pT0[i], y, t);
    }
    v2f z[3];
#pragma unroll
    for (int p = 0; p < 3; ++p) {
        v2f t = pk_fma(v[0], w.pW1[0 * 3 + p], w.pB1[p]);
        t = pk_fma(v[1], w.pW1[1 * 3 + p], t);
        t = pk_fma(v[2], w.pW1[2 * 3 + p], t);
        v2f y = tanh2p(K, t);
        z[p] = pk_fma(w.pT1[p], y, t);
    }
    v2f u3[3];
#pragma unroll
    for (int p = 0; p < 3; ++p) {
        v2f t = pk_fma(z[0], w.pW2[0 * 3 + p], w.pB2[p]);
        t = pk_fma(z[1], w.pW2[1 * 3 + p], t);
        t = pk_fma(z[2], w.pW2[2 * 3 + p], t);
        v2f y = tanh2p(K, t);
        u3[p] = pk_fma(w.pT2[p], y, t);
    }
    v2f s = pk_fma(u3[0], w.pW3h[0], w.pb3h);
    s = pk_fma(u3[1], w.pW3h[1], s);
    s = pk_fma(u3[2], w.pW3h[2], s);
    // sigmoid(sp)-sigmoid(sm) = 0.5*(tanh(sp/2)-tanh(sm/2)); the /2 is folded.
    v2f h = tanh2p(K, s);
    return 0.5f * (h.x - h.y);
}

__device__ __forceinline__ v2f dupf(float a) { v2f r; r.x = a; r.y = a; return r; }

__global__ __launch_bounds__(CHN, 1) void density_kernel(
    const float* __restrict__ x,
    const float* __restrict__ wt,
    float* __restrict__ out)
{
    const int c = threadIdx.x;          // thread <-> channel

    float W[NW];
#pragma unroll
    for (int s = 0; s < NW; ++s) W[s] = wt[s * CHN + c];   // 43 coalesced dwords

    WP w;
#pragma unroll
    for (int i = 0; i < 3; ++i) {
        float w0 = W[0 + i], bb = W[3 + i];
        w.pW0[i] = dupf(w0);
        w.pC0[i].x = fmaf(0.5f, w0, bb);
        w.pC0[i].y = fmaf(-0.5f, w0, bb);
        w.pT0[i] = dupf(W[6 + i]);
        w.pB1[i] = dupf(W[18 + i]);
        w.pT1[i] = dupf(W[21 + i]);
        w.pB2[i] = dupf(W[33 + i]);
        w.pT2[i] = dupf(W[36 + i]);
        w.pW3h[i] = dupf(0.5f * W[39 + i]);
    }
#pragma unroll
    for (int i = 0; i < 9; ++i) {
        w.pW1[i] = dupf(W[9 + i]);
        w.pW2[i] = dupf(W[24 + i]);
    }
    w.pb3h = dupf(0.5f * W[42]);

    Coef K;
    K.a1 = dupf(CF_A1); K.a3 = dupf(CF_A3); K.a5 = dupf(CF_A5); K.a7 = dupf(CF_A7);
    K.a9 = dupf(CF_A9); K.a11 = dupf(CF_A11); K.a13 = dupf(CF_A13);
    K.b0 = dupf(CF_B0); K.b2 = dupf(CF_B2); K.b4 = dupf(CF_B4); K.b6 = dupf(CF_B6);
    K.lo = -CF_TCLAMP; K.hi = CF_TCLAMP;

    // pin everything once (keep register-resident across the row loop)
#pragma unroll
    for (int i = 0; i < 3; ++i) {
        pin2(w.pW0[i]); pin2(w.pC0[i]); pin2(w.pT0[i]);
        pin2(w.pB1[i]); pin2(w.pT1[i]); pin2(w.pB2[i]); pin2(w.pT2[i]); pin2(w.pW3h[i]);
    }
#pragma unroll
    for (int i = 0; i < 9; ++i) { pin2(w.pW1[i]); pin2(w.pW2[i]); }
    pin2(w.pb3h);
    pin2(K.a1); pin2(K.a3); pin2(K.a5); pin2(K.a7); pin2(K.a9); pin2(K.a11); pin2(K.a13);
    pin2(K.b0); pin2(K.b2); pin2(K.b4); pin2(K.b6);
    pinf(K.lo); pinf(K.hi);

    const int b_start = blockIdx.x * ROWS_PER_BLOCK;
#pragma unroll 2
    for (int r = 0; r < ROWS_PER_BLOCK; ++r) {
        const int idx = (b_start + r) * CHN + c;
        out[idx] = density_pair(w, K, x[idx]);
    }
}

extern "C" void kernel_launch(void* const* d_in, const int* in_sizes, int n_in,
                              void* d_out, int out_size, void* d_ws, size_t ws_size,
                              hipStream_t stream) {
    const float* x  = (const float*)d_in[0];
    const float* a0 = (const float*)d_in[1];
    const float* a1 = (const float*)d_in[2];
    const float* a2 = (const float*)d_in[3];
    const float* b0 = (const float*)d_in[4];
    const float* b1 = (const float*)d_in[5];
    const float* b2 = (const float*)d_in[6];
    const float* b3 = (const float*)d_in[7];
    const float* H0 = (const float*)d_in[8];
    const float* H1 = (const float*)d_in[9];
    const float* H2 = (const float*)d_in[10];
    const float* H3 = (const float*)d_in[11];
    float* out = (float*)d_out;
    float* ws  = (float*)d_ws;   // needs NW*CHN*4 = 33 KB

    weights_kernel<<<1, CHN, 0, stream>>>(a0, a1, a2, b0, b1, b2, b3,
                                          H0, H1, H2, H3, ws);
    density_kernel<<<NBLOCKS, CHN, 0, stream>>>(x, ws, out);
}

// Round 9
// 81.762 us; speedup vs baseline: 1.6718x; 1.3743x over previous
//
#include <hip/hip_runtime.h>
#include <hip/hip_bf16.h>
#include <math.h>

#define CHN 192
#define BATCHN 65536
#define NBLOCKS 4096
#define ROWS_PER_BLOCK (BATCHN / NBLOCKS)   // 16
#define NWS 61                               // transformed-weight slots per channel

#define KSCALE 2.885390081777926f   // 2*log2(e)
#define LOG2E  1.4426950408889634f

// ---- fast device math -------------------------------------------------------
__device__ __forceinline__ float fast_rcp(float x)  { return __builtin_amdgcn_rcpf(x); }
__device__ __forceinline__ float fast_exp2(float x) { return __builtin_amdgcn_exp2f(x); }
__device__ __forceinline__ void pinf(float& v) { asm volatile("" : "+v"(v)); }

__device__ __forceinline__ float softplus_acc(float h) {
    if (h > 20.0f) return h;
    return log1pf(expf(h));
}

// ============================================================================
// Kernel A: transform weights ONCE into the scaled domain, slot-major in ws.
// Scaled domain: v' = K*v, K = 2*log2(e); exp2(t') = e^(2t);
// tanh(t) = 1 - 2*rcp(exp2(t')+1)  (sign-correct for all t; inf-safe: rcp(inf)=0).
// slot map (ws[s*CHN + c]):
//   0-2  W0K   3-5  B0K   6-8  cp    9-11 cm   12-14 gp  15-17 gm  18-20 T2_0
//   21-29 W1  30-32 B1K  33-35 T1K1 36-38 T2_1
//   39-47 W2  48-50 B2K  51-53 T1K2 54-56 T2_2
//   57-59 W3n 60 b3n
// ============================================================================
__global__ __launch_bounds__(CHN) void weights_kernel(
    const float* __restrict__ a0, const float* __restrict__ a1, const float* __restrict__ a2,
    const float* __restrict__ b0, const float* __restrict__ b1, const float* __restrict__ b2,
    const float* __restrict__ b3,
    const float* __restrict__ H0, const float* __restrict__ H1, const float* __restrict__ H2,
    const float* __restrict__ H3,
    float* __restrict__ ws)
{
    const int c = threadIdx.x;
#pragma unroll
    for (int i = 0; i < 3; ++i) {
        float w0k = KSCALE * softplus_acc(H0[c * 3 + i]);
        float h   = 0.5f * w0k;
        float t1k0 = KSCALE * tanhf(a0[c * 3 + i]);
        ws[(0  + i) * CHN + c] = w0k;
        ws[(3  + i) * CHN + c] = KSCALE * b0[c * 3 + i];
        ws[(6  + i) * CHN + c] = exp2f(h);
        ws[(9  + i) * CHN + c] = exp2f(-h);
        ws[(12 + i) * CHN + c] = h + t1k0;
        ws[(15 + i) * CHN + c] = -h + t1k0;
        ws[(18 + i) * CHN + c] = -2.0f * t1k0;

        float t1k1 = KSCALE * tanhf(a1[c * 3 + i]);
        ws[(30 + i) * CHN + c] = KSCALE * b1[c * 3 + i];
        ws[(33 + i) * CHN + c] = t1k1;
        ws[(36 + i) * CHN + c] = -2.0f * t1k1;

        float t1k2 = KSCALE * tanhf(a2[c * 3 + i]);
        ws[(48 + i) * CHN + c] = KSCALE * b2[c * 3 + i];
        ws[(51 + i) * CHN + c] = t1k2;
        ws[(54 + i) * CHN + c] = -2.0f * t1k2;

        ws[(57 + i) * CHN + c] = -0.5f * softplus_acc(H3[c * 3 + i]);
    }
#pragma unroll
    for (int i = 0; i < 9; ++i) {
        ws[(21 + i) * CHN + c] = softplus_acc(H1[c * 9 + i]);   // (C,3,3) [i][p]
        ws[(39 + i) * CHN + c] = softplus_acc(H2[c * 9 + i]);
    }
    ws[60 * CHN + c] = -LOG2E * b3[c];
}

// ============================================================================
// Kernel B: zero libm, scalar exp2/rcp on the quarter-rate trans pipe
// (overlaps VALU across waves), ~150 issue slots + 37 trans per element-pair.
// ============================================================================
__device__ __forceinline__ float density_pair(const float* __restrict__ W, float xv) {
    // ---- L0: one exp2 shared across the +/- CDF branches ----
    float vp[3], vm[3];
#pragma unroll
    for (int i = 0; i < 3; ++i) {
        float q  = fmaf(W[0 + i], xv, W[3 + i]);
        float E  = fast_exp2(q);
        float rp = fast_rcp(fmaf(E, W[6 + i], 1.0f));
        float rm = fast_rcp(fmaf(E, W[9 + i], 1.0f));
        vp[i] = fmaf(W[18 + i], rp, q + W[12 + i]);
        vm[i] = fmaf(W[18 + i], rm, q + W[15 + i]);
    }
    // ---- L1 ----
    float zp[3], zm[3];
#pragma unroll
    for (int p = 0; p < 3; ++p) {
        float tp = W[30 + p], tm = W[30 + p];
#pragma unroll
        for (int i = 0; i < 3; ++i) {
            tp = fmaf(vp[i], W[21 + i * 3 + p], tp);
            tm = fmaf(vm[i], W[21 + i * 3 + p], tm);
        }
        float rp = fast_rcp(fast_exp2(tp) + 1.0f);
        float rm = fast_rcp(fast_exp2(tm) + 1.0f);
        zp[p] = fmaf(W[36 + p], rp, tp + W[33 + p]);
        zm[p] = fmaf(W[36 + p], rm, tm + W[33 + p]);
    }
    // ---- L2 ----
    float yp[3], ym[3];
#pragma unroll
    for (int p = 0; p < 3; ++p) {
        float tp = W[48 + p], tm = W[48 + p];
#pragma unroll
        for (int i = 0; i < 3; ++i) {
            tp = fmaf(zp[i], W[39 + i * 3 + p], tp);
            tm = fmaf(zm[i], W[39 + i * 3 + p], tm);
        }
        float rp = fast_rcp(fast_exp2(tp) + 1.0f);
        float rm = fast_rcp(fast_exp2(tm) + 1.0f);
        yp[p] = fmaf(W[54 + p], rp, tp + W[51 + p]);
        ym[p] = fmaf(W[54 + p], rm, tm + W[51 + p]);
    }
    // ---- L3 + sigmoid (s'' = -log2e*s; p = rcp(exp2(s'')+1)) ----
    float sp = W[60], sm = W[60];
#pragma unroll
    for (int i = 0; i < 3; ++i) {
        sp = fmaf(yp[i], W[57 + i], sp);
        sm = fmaf(ym[i], W[57 + i], sm);
    }
    float pp = fast_rcp(fast_exp2(sp) + 1.0f);
    float pm = fast_rcp(fast_exp2(sm) + 1.0f);
    return pp - pm;
}

__global__ __launch_bounds__(CHN) void density_kernel(
    const float* __restrict__ x,
    const float* __restrict__ wt,
    float* __restrict__ out)
{
    const int c = threadIdx.x;          // thread <-> channel

    float W[NWS];
#pragma unroll
    for (int s = 0; s < NWS; ++s) W[s] = wt[s * CHN + c];   // 61 coalesced dwords
#pragma unroll
    for (int s = 0; s < NWS; ++s) pinf(W[s]);               // keep register-resident

    const int b_start = blockIdx.x * ROWS_PER_BLOCK;
#pragma unroll 2
    for (int r = 0; r < ROWS_PER_BLOCK; ++r) {
        const int idx = (b_start + r) * CHN + c;
        out[idx] = density_pair(W, x[idx]);
    }
}

extern "C" void kernel_launch(void* const* d_in, const int* in_sizes, int n_in,
                              void* d_out, int out_size, void* d_ws, size_t ws_size,
                              hipStream_t stream) {
    const float* x  = (const float*)d_in[0];
    const float* a0 = (const float*)d_in[1];
    const float* a1 = (const float*)d_in[2];
    const float* a2 = (const float*)d_in[3];
    const float* b0 = (const float*)d_in[4];
    const float* b1 = (const float*)d_in[5];
    const float* b2 = (const float*)d_in[6];
    const float* b3 = (const float*)d_in[7];
    const float* H0 = (const float*)d_in[8];
    const float* H1 = (const float*)d_in[9];
    const float* H2 = (const float*)d_in[10];
    const float* H3 = (const float*)d_in[11];
    float* out = (float*)d_out;
    float* ws  = (float*)d_ws;   // needs NWS*CHN*4 = 46.9 KB

    weights_kernel<<<1, CHN, 0, stream>>>(a0, a1, a2, b0, b1, b2, b3,
                                          H0, H1, H2, H3, ws);
    density_kernel<<<NBLOCKS, CHN, 0, stream>>>(x, ws, out);
}